// Round 15
// baseline (623.527 us; speedup 1.0000x reference)
//
#include <hip/hip_runtime.h>
#include <math.h>

#define NNODES 50000
#define NEDGES 200000

typedef unsigned short ushort_t;
using frag8 = __attribute__((ext_vector_type(8))) short;   // 8 x bf16
using facc4 = __attribute__((ext_vector_type(4))) float;   // 4 x f32

// ---------- bf16 helpers (bit-level, RNE) ----------
static __device__ __forceinline__ ushort_t f2b(float f) {
  union { float f; unsigned u; } v; v.f = f;
  unsigned r = v.u + 0x7FFFu + ((v.u >> 16) & 1u);
  return (ushort_t)(r >> 16);
}
static __device__ __forceinline__ float b2f(unsigned hi) {
  return __uint_as_float(hi << 16);
}
static __device__ __forceinline__ void unpack8(const int4 v, float* f) {
  f[0] = b2f((unsigned)v.x & 0xFFFFu); f[1] = b2f((unsigned)v.x >> 16);
  f[2] = b2f((unsigned)v.y & 0xFFFFu); f[3] = b2f((unsigned)v.y >> 16);
  f[4] = b2f((unsigned)v.z & 0xFFFFu); f[5] = b2f((unsigned)v.z >> 16);
  f[6] = b2f((unsigned)v.w & 0xFFFFu); f[7] = b2f((unsigned)v.w >> 16);
}
static __device__ __forceinline__ void stf(float* p, float v) { *p = v; }
static __device__ __forceinline__ void stf(ushort_t* p, float v) { *p = f2b(v); }

// ---------- cast x (fp32) -> bf16, 8 elems/thread ----------
__global__ void cast_x(const float* __restrict__ x, ushort_t* __restrict__ xb, int total8) {
  int t = blockIdx.x * 256 + threadIdx.x;
  if (t >= total8) return;
  const float4* p = (const float4*)(x + (size_t)t * 8);
  float4 a = p[0], b = p[1];
  int4 w = make_int4(
      (int)((unsigned)f2b(a.x) | ((unsigned)f2b(a.y) << 16)),
      (int)((unsigned)f2b(a.z) | ((unsigned)f2b(a.w) << 16)),
      (int)((unsigned)f2b(b.x) | ((unsigned)f2b(b.y) << 16)),
      (int)((unsigned)f2b(b.z) | ((unsigned)f2b(b.w) << 16)));
  *(int4*)(xb + (size_t)t * 8) = w;
}

// ---------- tiled transpose+cast: WtLR[c2][k] = bf16(W{l,r}[k][c]) ----------
// 32x32 tile via LDS; both global read and write coalesced.
__global__ __launch_bounds__(256) void wt_prep_t(
    const float* __restrict__ Wl, const float* __restrict__ Wr,
    ushort_t* __restrict__ WtLR, int K, int Mo) {
  __shared__ float tile[32][33];
  const int tx = threadIdx.x & 31, ty = threadIdx.x >> 5;   // 32 x 8
  const int kb = blockIdx.y * 32, cb = blockIdx.x * 32;
  const int c2 = cb + tx;
  const float* W = (c2 < Mo) ? Wl : Wr;
  const int col = (c2 < Mo) ? c2 : c2 - Mo;
  #pragma unroll
  for (int r = 0; r < 4; ++r)
    tile[ty * 4 + r][tx] = W[(size_t)(kb + ty * 4 + r) * Mo + col];
  __syncthreads();
  #pragma unroll
  for (int r = 0; r < 4; ++r) {
    const int c2w = cb + ty * 4 + r;
    WtLR[(size_t)c2w * K + kb + tx] = f2b(tile[tx][ty * 4 + r]);
  }
}

// ===== PF64 GEMM: BK=64 (half the barriers) + 1-deep register prefetch =====
__global__ __launch_bounds__(256) void gemm2_pf64(
    const ushort_t* __restrict__ A, const ushort_t* __restrict__ WtLR,
    const float* __restrict__ bl, const float* __restrict__ br,
    ushort_t* __restrict__ xlb, ushort_t* __restrict__ xrb,
    int N, int K, int Mo, int ncb) {
  // union: Al[8][128][8] 16KB + Bl[8][128][8] 16KB = 32KB  /  Cl[128][136] 34816B
  __shared__ __align__(16) char smem[34816];
  auto Al = reinterpret_cast<ushort_t(*)[128][8]>(smem);           // [8][128][8]
  auto Bl = reinterpret_cast<ushort_t(*)[128][8]>(smem + 16384);   // [8][128][8]
  auto Cl = reinterpret_cast<ushort_t(*)[136]>(smem);              // [128][136]

  // bijective XCD-chunked swizzle
  const int nwg = gridDim.x;
  const int q = nwg >> 3, r = nwg & 7;
  const int xcd = blockIdx.x & 7, pos = blockIdx.x >> 3;
  const int orig = (xcd < r ? xcd * (q + 1) : r * (q + 1) + (xcd - r) * q) + pos;
  const int rp = orig / ncb, cb = orig - rp * ncb;
  const int brow = rp * 128;
  const int bcol = cb * 128;

  const int tid = threadIdx.x;
  const int w = tid >> 6, lane = tid & 63;
  const int wr = w >> 1, wc = w & 1;
  const int l15 = lane & 15, l4 = lane >> 4;

  facc4 acc[4][4] = {};

  const int srow = tid >> 1;              // 0..127
  const int sk4  = (tid & 1) * 4;         // plane base 0 or 4 (k offset 0/32)
  const int grow = brow + srow;
  const bool rowok = grow < N;
  const ushort_t* pa = A + (size_t)(rowok ? grow : 0) * K + sk4 * 8;
  const ushort_t* pb = WtLR + (size_t)(bcol + srow) * K + sk4 * 8;

  const int nt = K >> 6;                  // 2 or 8

  // staging registers: 4 int4 A + 4 int4 B (one tile)
  int4 ar[4], br_[4];
  if (rowok) {
    const int4* p = (const int4*)pa;
    ar[0] = p[0]; ar[1] = p[1]; ar[2] = p[2]; ar[3] = p[3];
  } else {
    ar[0] = ar[1] = ar[2] = ar[3] = make_int4(0, 0, 0, 0);
  }
  { const int4* p = (const int4*)pb;
    br_[0] = p[0]; br_[1] = p[1]; br_[2] = p[2]; br_[3] = p[3]; }

  for (int t = 0; t < nt; ++t) {
    // stage current tile from regs (auto vmcnt waits only for tile-t loads)
    #pragma unroll
    for (int j = 0; j < 4; ++j) {
      *(int4*)&Al[sk4 + j][srow][0] = ar[j];
      *(int4*)&Bl[sk4 + j][srow][0] = br_[j];
    }
    // issue next tile's loads -> regs (fly under barrier+ds_read+MFMA)
    if (t + 1 < nt) {
      const int k0 = (t + 1) * 64;
      if (rowok) {
        const int4* p = (const int4*)(pa + k0);
        ar[0] = p[0]; ar[1] = p[1]; ar[2] = p[2]; ar[3] = p[3];
      }
      { const int4* p = (const int4*)(pb + k0);
        br_[0] = p[0]; br_[1] = p[1]; br_[2] = p[2]; br_[3] = p[3]; }
    }
    __syncthreads();
    #pragma unroll
    for (int kk = 0; kk < 2; ++kk) {
      frag8 af[4], bfg[4];
      #pragma unroll
      for (int i = 0; i < 4; ++i)
        af[i] = *(const frag8*)&Al[kk * 4 + l4][wr * 64 + i * 16 + l15][0];
      #pragma unroll
      for (int j = 0; j < 4; ++j)
        bfg[j] = *(const frag8*)&Bl[kk * 4 + l4][wc * 64 + j * 16 + l15][0];
      #pragma unroll
      for (int i = 0; i < 4; ++i)
        #pragma unroll
        for (int j = 0; j < 4; ++j)
          acc[i][j] = __builtin_amdgcn_mfma_f32_16x16x32_bf16(af[i], bfg[j], acc[i][j], 0, 0, 0);
    }
    __syncthreads();
  }

  // ---- epilogue: full-tile LDS stage, coalesced int4 writeout ----
  #pragma unroll
  for (int j = 0; j < 4; ++j) {
    const int lcol = wc * 64 + j * 16 + l15;
    const int col2 = bcol + lcol;
    const float bv = (col2 < Mo) ? bl[col2] : br[col2 - Mo];
    #pragma unroll
    for (int i = 0; i < 4; ++i) {
      const int lrow = wr * 64 + i * 16 + l4 * 4;
      #pragma unroll
      for (int rr = 0; rr < 4; ++rr)
        Cl[lrow + rr][lcol] = f2b(acc[i][j][rr] + bv);
    }
  }
  __syncthreads();
  {
    const int row = tid >> 1;
    const int half = tid & 1;
    const int growo = brow + row;
    if (growo < N) {
      const int colb = half * 64;
      const int col2 = bcol + colb;
      const bool isL = col2 < Mo;
      ushort_t* dst = (isL ? xlb : xrb) + (size_t)growo * Mo + (isL ? col2 : col2 - Mo);
      #pragma unroll
      for (int k = 0; k < 8; ++k) {
        int4 v = *(const int4*)&Cl[row][colb + k * 8];
        *(int4*)(dst + k * 8) = v;
      }
    }
  }
}

// ---------- CSR build (by dst) ----------
__global__ void csr_zero(int* __restrict__ deg) {
  int t = blockIdx.x * blockDim.x + threadIdx.x;
  if (t < NNODES) deg[t] = 0;
}
__global__ void csr_hist(const int* __restrict__ ei, int* __restrict__ deg) {
  int e = blockIdx.x * blockDim.x + threadIdx.x;
  if (e >= NEDGES) return;
  atomicAdd(&deg[ei[NEDGES + e]], 1);
}

#define SCAN_TPB 256
#define SCAN_EPT 4
#define SCAN_CHUNK (SCAN_TPB * SCAN_EPT)                       // 1024
#define SCAN_BLK ((NNODES + SCAN_CHUNK - 1) / SCAN_CHUNK)      // 49

__global__ __launch_bounds__(SCAN_TPB) void scan_k1(const int* __restrict__ deg,
                                                    int* __restrict__ bsum) {
  __shared__ int sd[SCAN_TPB];
  const int tid = threadIdx.x;
  const int tbase = blockIdx.x * SCAN_CHUNK + tid * SCAN_EPT;
  int s = 0;
  #pragma unroll
  for (int j = 0; j < SCAN_EPT; ++j) {
    int idx = tbase + j;
    if (idx < NNODES) s += deg[idx];
  }
  sd[tid] = s;
  __syncthreads();
  for (int d = SCAN_TPB / 2; d > 0; d >>= 1) {
    if (tid < d) sd[tid] += sd[tid + d];
    __syncthreads();
  }
  if (tid == 0) bsum[blockIdx.x] = sd[0];
}

__global__ __launch_bounds__(64) void scan_k2(const int* __restrict__ bsum,
                                              int* __restrict__ bpref,
                                              int* __restrict__ off) {
  __shared__ int sd[64];
  const int tid = threadIdx.x;
  sd[tid] = (tid < SCAN_BLK) ? bsum[tid] : 0;
  __syncthreads();
  for (int d = 1; d < 64; d <<= 1) {
    int t = (tid >= d) ? sd[tid - d] : 0;
    __syncthreads();
    sd[tid] += t;
    __syncthreads();
  }
  if (tid < SCAN_BLK) bpref[tid] = (tid == 0) ? 0 : sd[tid - 1];
  if (tid == 0) off[NNODES] = NEDGES;
}

__global__ __launch_bounds__(SCAN_TPB) void scan_k3(const int* __restrict__ deg,
                                                    const int* __restrict__ bpref,
                                                    int* __restrict__ off,
                                                    int* __restrict__ pos) {
  __shared__ int sd[SCAN_TPB];
  const int tid = threadIdx.x;
  const int tbase = blockIdx.x * SCAN_CHUNK + tid * SCAN_EPT;
  int v[SCAN_EPT];
  int s = 0;
  #pragma unroll
  for (int j = 0; j < SCAN_EPT; ++j) {
    int idx = tbase + j;
    v[j] = (idx < NNODES) ? deg[idx] : 0;
    s += v[j];
  }
  sd[tid] = s;
  __syncthreads();
  for (int d = 1; d < SCAN_TPB; d <<= 1) {
    int t = (tid >= d) ? sd[tid - d] : 0;
    __syncthreads();
    sd[tid] += t;
    __syncthreads();
  }
  int run = bpref[blockIdx.x] + ((tid == 0) ? 0 : sd[tid - 1]);
  #pragma unroll
  for (int j = 0; j < SCAN_EPT; ++j) {
    int idx = tbase + j;
    if (idx < NNODES) { off[idx] = run; pos[idx] = run; run += v[j]; }
  }
}

// stores SRC node id directly
__global__ void csr_fill(const int* __restrict__ ei, int* __restrict__ pos,
                         int* __restrict__ srcs) {
  int e = blockIdx.x * blockDim.x + threadIdx.x;
  if (e >= NEDGES) return;
  int p = atomicAdd(&pos[ei[NEDGES + e]], 1);
  srcs[p] = ei[e];
}

// ---------- fused attention + online-softmax aggregation, one wave/node ----------
// 2-deep dependent-chain prefetch: srcs[i+2] index + row i+1 gather in flight.
template<int H, int C, bool ELU, typename TO>
__global__ __launch_bounds__(256) void csr_fused(
    const int* __restrict__ off, const int* __restrict__ srcs,
    const ushort_t* __restrict__ xl, const ushort_t* __restrict__ xr,
    const float* __restrict__ att, const float* __restrict__ bias,
    TO* __restrict__ out) {
  constexpr int HC = H * C;
  constexpr int CPL = HC / 64;
  constexpr int GROUP = C / CPL;
  const int n = (blockIdx.x * blockDim.x + threadIdx.x) >> 6;
  const int lane = threadIdx.x & 63;
  if (n >= NNODES) return;
  const int s0 = off[n], s1 = off[n + 1];

  float xrr[CPL], atr[CPL];
  if constexpr (CPL == 8) {
    unpack8(*(const int4*)(xr + (size_t)n * HC + lane * 8), xrr);
    const float4 a0 = *(const float4*)(att + lane * 8);
    const float4 a1 = *(const float4*)(att + lane * 8 + 4);
    atr[0] = a0.x; atr[1] = a0.y; atr[2] = a0.z; atr[3] = a0.w;
    atr[4] = a1.x; atr[5] = a1.y; atr[6] = a1.z; atr[7] = a1.w;
  } else {
    xrr[0] = b2f(xr[(size_t)n * HC + lane]);
    atr[0] = att[lane];
  }

  float m = -1e30f, s = 0.f;
  float acc[CPL] = {};

  int4 vnext = make_int4(0, 0, 0, 0);
  ushort_t unext = 0;
  int snext = 0;
  if (s0 < s1) {
    const int srcn = srcs[s0];
    if constexpr (CPL == 8) vnext = *(const int4*)(xl + (size_t)srcn * HC + lane * 8);
    else                    unext = xl[(size_t)srcn * HC + lane];
    if (s0 + 1 < s1) snext = srcs[s0 + 1];
  }
  for (int i = s0; i < s1; ++i) {
    int4 vcur = vnext; ushort_t ucur = unext;
    const int sn = snext;
    if (i + 2 < s1) snext = srcs[i + 2];       // index for iter i+2 (independent)
    if (i + 1 < s1) {                          // gather row i+1 (src already in reg)
      if constexpr (CPL == 8) vnext = *(const int4*)(xl + (size_t)sn * HC + lane * 8);
      else                    unext = xl[(size_t)sn * HC + lane];
    }
    float zl[CPL];
    if constexpr (CPL == 8) unpack8(vcur, zl);
    else zl[0] = b2f(ucur);
    float e = 0.f;
    #pragma unroll
    for (int c = 0; c < CPL; ++c) {
      float z = zl[c] + xrr[c];
      z = (z > 0.f) ? z : 0.2f * z;
      e += z * atr[c];
    }
    #pragma unroll
    for (int o = 1; o < GROUP; o <<= 1)
      e += __shfl_xor(e, o, 64);
    if (e > m) {
      const float scale = __expf(m - e);
      s *= scale;
      #pragma unroll
      for (int c = 0; c < CPL; ++c) acc[c] *= scale;
      m = e;
    }
    const float w = __expf(e - m);
    s += w;
    #pragma unroll
    for (int c = 0; c < CPL; ++c) acc[c] += w * zl[c];
  }
  const float inv = 1.f / (s + 1e-16f);
  TO* po = out + (size_t)n * HC + lane * CPL;
  #pragma unroll
  for (int c = 0; c < CPL; ++c) {
    float v = acc[c] * inv + bias[lane * CPL + c];
    if (ELU) v = v > 0.f ? v : (__expf(v) - 1.f);
    stf(&po[c], v);
  }
}

// ---------- emergency: report ws_size via absmax ----------
__global__ void report_ws(float* __restrict__ out, float v) { out[0] = v; }

// ---------- orchestration ----------
extern "C" void kernel_launch(void* const* d_in, const int* in_sizes, int n_in,
                              void* d_out, int out_size, void* d_ws, size_t ws_size,
                              hipStream_t stream) {
  const float* x  = (const float*)d_in[0];
  const int*   ei = (const int*)d_in[1];
  float* out = (float*)d_out;
  char* ws = (char*)d_ws;

  ushort_t* hbuf = (ushort_t*)(ws);                   // N*512 bf16  51,200,000
  ushort_t* xlb  = (ushort_t*)(ws + 51200000ull);     // N*512 bf16
  ushort_t* xrb  = (ushort_t*)(ws + 102400000ull);    // N*512 bf16
  ushort_t* xb   = (ushort_t*)(ws + 153600000ull);    // N*128 bf16
  ushort_t* WtLR = (ushort_t*)(ws + 166400000ull);    // <=2MB
  int* bsum  = (int*)(ws + 168500000ull);
  int* bpref = (int*)(ws + 168501024ull);
  int* coff  = (int*)(ws + 168600000ull);             // N+1
  int* cpos  = (int*)(ws + 168800008ull);             // N
  int* cdeg  = (int*)(ws + 169000012ull);             // N
  int* srcs  = (int*)(ws + 169200016ull);             // E -> end 170,000,016

  if (ws_size < 170000016ull) {
    report_ws<<<1, 1, 0, stream>>>(out, (float)ws_size);
    return;
  }

  cast_x<<<(NNODES * 128 / 8 + 255) / 256, 256, 0, stream>>>(x, xb, NNODES * 128 / 8);
  csr_zero<<<(NNODES + 255) / 256, 256, 0, stream>>>(cdeg);
  csr_hist<<<(NEDGES + 255) / 256, 256, 0, stream>>>(ei, cdeg);
  scan_k1<<<SCAN_BLK, SCAN_TPB, 0, stream>>>(cdeg, bsum);
  scan_k2<<<1, 64, 0, stream>>>(bsum, bpref, coff);
  scan_k3<<<SCAN_BLK, SCAN_TPB, 0, stream>>>(cdeg, bpref, coff, cpos);
  csr_fill<<<(NEDGES + 255) / 256, 256, 0, stream>>>(ei, cpos, srcs);

  const int ngrid = (NNODES * 64 + 255) / 256;
  const int nrp = (NNODES + 127) / 128;               // 391 row panels

  for (int layer = 0; layer < 4; ++layer) {
    const int base = 2 + layer * 6;
    const float* Wl  = (const float*)d_in[base + 0];
    const float* bl  = (const float*)d_in[base + 1];
    const float* Wr  = (const float*)d_in[base + 2];
    const float* br  = (const float*)d_in[base + 3];
    const float* att = (const float*)d_in[base + 4];
    const float* b   = (const float*)d_in[base + 5];

    const ushort_t* A = (layer == 0) ? xb : hbuf;
    const int K  = (layer == 0) ? 128 : 512;
    const int Mo = (layer == 3) ? 64 : 512;
    const int ncb = 2 * Mo / 128;

    dim3 wg(2 * Mo / 32, K / 32);
    wt_prep_t<<<wg, 256, 0, stream>>>(Wl, Wr, WtLR, K, Mo);

    gemm2_pf64<<<ncb * nrp, 256, 0, stream>>>(A, WtLR, bl, br, xlb, xrb,
                                              NNODES, K, Mo, ncb);

    if (layer < 3) {
      csr_fused<4, 128, true, ushort_t><<<ngrid, 256, 0, stream>>>(
          coff, srcs, xlb, xrb, att, b, hbuf);
    } else {
      csr_fused<1, 64, false, float><<<ngrid, 256, 0, stream>>>(
          coff, srcs, xlb, xrb, att, b, out);
    }
  }
}

// Round 16
// 453.482 us; speedup vs baseline: 1.3750x; 1.3750x over previous
//
#include <hip/hip_runtime.h>
#include <math.h>

#define NNODES 50000
#define NEDGES 200000

typedef unsigned short ushort_t;
using frag8 = __attribute__((ext_vector_type(8))) short;   // 8 x bf16
using facc4 = __attribute__((ext_vector_type(4))) float;   // 4 x f32

// ---------- bf16 helpers (bit-level, RNE) ----------
static __device__ __forceinline__ ushort_t f2b(float f) {
  union { float f; unsigned u; } v; v.f = f;
  unsigned r = v.u + 0x7FFFu + ((v.u >> 16) & 1u);
  return (ushort_t)(r >> 16);
}
static __device__ __forceinline__ float b2f(unsigned hi) {
  return __uint_as_float(hi << 16);
}
static __device__ __forceinline__ void unpack8(const int4 v, float* f) {
  f[0] = b2f((unsigned)v.x & 0xFFFFu); f[1] = b2f((unsigned)v.x >> 16);
  f[2] = b2f((unsigned)v.y & 0xFFFFu); f[3] = b2f((unsigned)v.y >> 16);
  f[4] = b2f((unsigned)v.z & 0xFFFFu); f[5] = b2f((unsigned)v.z >> 16);
  f[6] = b2f((unsigned)v.w & 0xFFFFu); f[7] = b2f((unsigned)v.w >> 16);
}
static __device__ __forceinline__ void stf(float* p, float v) { *p = v; }
static __device__ __forceinline__ void stf(ushort_t* p, float v) { *p = f2b(v); }

// ---------- cast x (fp32) -> bf16, 8 elems/thread ----------
__global__ void cast_x(const float* __restrict__ x, ushort_t* __restrict__ xb, int total8) {
  int t = blockIdx.x * 256 + threadIdx.x;
  if (t >= total8) return;
  const float4* p = (const float4*)(x + (size_t)t * 8);
  float4 a = p[0], b = p[1];
  int4 w = make_int4(
      (int)((unsigned)f2b(a.x) | ((unsigned)f2b(a.y) << 16)),
      (int)((unsigned)f2b(a.z) | ((unsigned)f2b(a.w) << 16)),
      (int)((unsigned)f2b(b.x) | ((unsigned)f2b(b.y) << 16)),
      (int)((unsigned)f2b(b.z) | ((unsigned)f2b(b.w) << 16)));
  *(int4*)(xb + (size_t)t * 8) = w;
}

// ---------- tiled transpose+cast: WtLR[c2][k] = bf16(W{l,r}[k][c]) ----------
__global__ __launch_bounds__(256) void wt_prep_t(
    const float* __restrict__ Wl, const float* __restrict__ Wr,
    ushort_t* __restrict__ WtLR, int K, int Mo) {
  __shared__ float tile[32][33];
  const int tx = threadIdx.x & 31, ty = threadIdx.x >> 5;   // 32 x 8
  const int kb = blockIdx.y * 32, cb = blockIdx.x * 32;
  const int c2 = cb + tx;
  const float* W = (c2 < Mo) ? Wl : Wr;
  const int col = (c2 < Mo) ? c2 : c2 - Mo;
  #pragma unroll
  for (int r = 0; r < 4; ++r)
    tile[ty * 4 + r][tx] = W[(size_t)(kb + ty * 4 + r) * Mo + col];
  __syncthreads();
  #pragma unroll
  for (int r = 0; r < 4; ++r) {
    const int c2w = cb + ty * 4 + r;
    WtLR[(size_t)c2w * K + kb + tx] = f2b(tile[tx][ty * 4 + r]);
  }
}

// ===== PF2 GEMM (round-14 verbatim): BK=32, two-deep register prefetch =====
__global__ __launch_bounds__(256) void gemm2_pf2(
    const ushort_t* __restrict__ A, const ushort_t* __restrict__ WtLR,
    const float* __restrict__ bl, const float* __restrict__ br,
    ushort_t* __restrict__ xlb, ushort_t* __restrict__ xrb,
    int N, int K, int Mo, int ncb) {
  __shared__ __align__(16) char smem[34816];   // union: Al+Bl (16KB) / Cl (34KB)
  auto Al = reinterpret_cast<ushort_t(*)[128][8]>(smem);
  auto Bl = reinterpret_cast<ushort_t(*)[128][8]>(smem + 8192);
  auto Cl = reinterpret_cast<ushort_t(*)[136]>(smem);

  const int nwg = gridDim.x;
  const int q = nwg >> 3, r = nwg & 7;
  const int xcd = blockIdx.x & 7, pos = blockIdx.x >> 3;
  const int orig = (xcd < r ? xcd * (q + 1) : r * (q + 1) + (xcd - r) * q) + pos;
  const int rp = orig / ncb, cb = orig - rp * ncb;
  const int brow = rp * 128;
  const int bcol = cb * 128;

  const int tid = threadIdx.x;
  const int w = tid >> 6, lane = tid & 63;
  const int wr = w >> 1, wc = w & 1;
  const int l15 = lane & 15, l4 = lane >> 4;

  facc4 acc[4][4] = {};

  const int srow = tid >> 1;
  const int skb  = (tid & 1) * 2;
  const int grow = brow + srow;
  const bool rowok = grow < N;
  const ushort_t* pa = A + (size_t)(rowok ? grow : 0) * K + skb * 8;
  const ushort_t* pb = WtLR + (size_t)(bcol + srow) * K + skb * 8;

  const int nt = K >> 5;                        // always even (4 or 16)

  int4 a00, a01, b00, b01;   // set 0
  int4 a10, a11, b10, b11;   // set 1
  if (rowok) { const int4* p = (const int4*)pa; a00 = p[0]; a01 = p[1]; }
  else       { a00 = a01 = make_int4(0, 0, 0, 0); }
  { const int4* p = (const int4*)pb; b00 = p[0]; b01 = p[1]; }
  if (rowok) { const int4* p = (const int4*)(pa + 32); a10 = p[0]; a11 = p[1]; }
  else       { a10 = a11 = make_int4(0, 0, 0, 0); }
  { const int4* p = (const int4*)(pb + 32); b10 = p[0]; b11 = p[1]; }

#define PF2_BODY(AS0, AS1, BS0, BS1, T)                                        \
  {                                                                            \
    *(int4*)&Al[skb + 0][srow][0] = AS0;                                       \
    *(int4*)&Al[skb + 1][srow][0] = AS1;                                       \
    *(int4*)&Bl[skb + 0][srow][0] = BS0;                                       \
    *(int4*)&Bl[skb + 1][srow][0] = BS1;                                       \
    if ((T) + 2 < nt) {                                                        \
      const int k0 = ((T) + 2) * 32;                                           \
      if (rowok) { const int4* p = (const int4*)(pa + k0); AS0 = p[0]; AS1 = p[1]; } \
      { const int4* p = (const int4*)(pb + k0); BS0 = p[0]; BS1 = p[1]; }      \
    }                                                                          \
    __syncthreads();                                                           \
    frag8 af[4], bfg[4];                                                       \
    _Pragma("unroll")                                                          \
    for (int i = 0; i < 4; ++i)                                                \
      af[i] = *(const frag8*)&Al[l4][wr * 64 + i * 16 + l15][0];               \
    _Pragma("unroll")                                                          \
    for (int j = 0; j < 4; ++j)                                                \
      bfg[j] = *(const frag8*)&Bl[l4][wc * 64 + j * 16 + l15][0];              \
    _Pragma("unroll")                                                          \
    for (int i = 0; i < 4; ++i)                                                \
      _Pragma("unroll")                                                        \
      for (int j = 0; j < 4; ++j)                                              \
        acc[i][j] = __builtin_amdgcn_mfma_f32_16x16x32_bf16(af[i], bfg[j],     \
                                                            acc[i][j], 0, 0, 0); \
    __syncthreads();                                                           \
  }

  for (int t = 0; t < nt; t += 2) {
    PF2_BODY(a00, a01, b00, b01, t);
    PF2_BODY(a10, a11, b10, b11, t + 1);
  }
#undef PF2_BODY

  #pragma unroll
  for (int j = 0; j < 4; ++j) {
    const int lcol = wc * 64 + j * 16 + l15;
    const int col2 = bcol + lcol;
    const float bv = (col2 < Mo) ? bl[col2] : br[col2 - Mo];
    #pragma unroll
    for (int i = 0; i < 4; ++i) {
      const int lrow = wr * 64 + i * 16 + l4 * 4;
      #pragma unroll
      for (int rr = 0; rr < 4; ++rr)
        Cl[lrow + rr][lcol] = f2b(acc[i][j][rr] + bv);
    }
  }
  __syncthreads();
  {
    const int row = tid >> 1;
    const int half = tid & 1;
    const int growo = brow + row;
    if (growo < N) {
      const int colb = half * 64;
      const int col2 = bcol + colb;
      const bool isL = col2 < Mo;
      ushort_t* dst = (isL ? xlb : xrb) + (size_t)growo * Mo + (isL ? col2 : col2 - Mo);
      #pragma unroll
      for (int k = 0; k < 8; ++k) {
        int4 v = *(const int4*)&Cl[row][colb + k * 8];
        *(int4*)(dst + k * 8) = v;
      }
    }
  }
}

// ---------- CSR build (by dst) ----------
__global__ void csr_zero(int* __restrict__ deg) {
  int t = blockIdx.x * blockDim.x + threadIdx.x;
  if (t < NNODES) deg[t] = 0;
}
__global__ void csr_hist(const int* __restrict__ ei, int* __restrict__ deg) {
  int e = blockIdx.x * blockDim.x + threadIdx.x;
  if (e >= NEDGES) return;
  atomicAdd(&deg[ei[NEDGES + e]], 1);
}

#define SCAN_TPB 256
#define SCAN_EPT 4
#define SCAN_CHUNK (SCAN_TPB * SCAN_EPT)                       // 1024
#define SCAN_BLK ((NNODES + SCAN_CHUNK - 1) / SCAN_CHUNK)      // 49

__global__ __launch_bounds__(SCAN_TPB) void scan_k1(const int* __restrict__ deg,
                                                    int* __restrict__ bsum) {
  __shared__ int sd[SCAN_TPB];
  const int tid = threadIdx.x;
  const int tbase = blockIdx.x * SCAN_CHUNK + tid * SCAN_EPT;
  int s = 0;
  #pragma unroll
  for (int j = 0; j < SCAN_EPT; ++j) {
    int idx = tbase + j;
    if (idx < NNODES) s += deg[idx];
  }
  sd[tid] = s;
  __syncthreads();
  for (int d = SCAN_TPB / 2; d > 0; d >>= 1) {
    if (tid < d) sd[tid] += sd[tid + d];
    __syncthreads();
  }
  if (tid == 0) bsum[blockIdx.x] = sd[0];
}

__global__ __launch_bounds__(64) void scan_k2(const int* __restrict__ bsum,
                                              int* __restrict__ bpref,
                                              int* __restrict__ off) {
  __shared__ int sd[64];
  const int tid = threadIdx.x;
  sd[tid] = (tid < SCAN_BLK) ? bsum[tid] : 0;
  __syncthreads();
  for (int d = 1; d < 64; d <<= 1) {
    int t = (tid >= d) ? sd[tid - d] : 0;
    __syncthreads();
    sd[tid] += t;
    __syncthreads();
  }
  if (tid < SCAN_BLK) bpref[tid] = (tid == 0) ? 0 : sd[tid - 1];
  if (tid == 0) off[NNODES] = NEDGES;
}

__global__ __launch_bounds__(SCAN_TPB) void scan_k3(const int* __restrict__ deg,
                                                    const int* __restrict__ bpref,
                                                    int* __restrict__ off,
                                                    int* __restrict__ pos) {
  __shared__ int sd[SCAN_TPB];
  const int tid = threadIdx.x;
  const int tbase = blockIdx.x * SCAN_CHUNK + tid * SCAN_EPT;
  int v[SCAN_EPT];
  int s = 0;
  #pragma unroll
  for (int j = 0; j < SCAN_EPT; ++j) {
    int idx = tbase + j;
    v[j] = (idx < NNODES) ? deg[idx] : 0;
    s += v[j];
  }
  sd[tid] = s;
  __syncthreads();
  for (int d = 1; d < SCAN_TPB; d <<= 1) {
    int t = (tid >= d) ? sd[tid - d] : 0;
    __syncthreads();
    sd[tid] += t;
    __syncthreads();
  }
  int run = bpref[blockIdx.x] + ((tid == 0) ? 0 : sd[tid - 1]);
  #pragma unroll
  for (int j = 0; j < SCAN_EPT; ++j) {
    int idx = tbase + j;
    if (idx < NNODES) { off[idx] = run; pos[idx] = run; run += v[j]; }
  }
}

// stores SRC node id directly
__global__ void csr_fill(const int* __restrict__ ei, int* __restrict__ pos,
                         int* __restrict__ srcs) {
  int e = blockIdx.x * blockDim.x + threadIdx.x;
  if (e >= NEDGES) return;
  int p = atomicAdd(&pos[ei[NEDGES + e]], 1);
  srcs[p] = ei[e];
}

// ---------- fused attention + online-softmax aggregation, one wave/node ----------
// 2-deep dependent-chain prefetch: srcs[i+2] index + row i+1 gather in flight.
template<int H, int C, bool ELU, typename TO>
__global__ __launch_bounds__(256) void csr_fused(
    const int* __restrict__ off, const int* __restrict__ srcs,
    const ushort_t* __restrict__ xl, const ushort_t* __restrict__ xr,
    const float* __restrict__ att, const float* __restrict__ bias,
    TO* __restrict__ out) {
  constexpr int HC = H * C;
  constexpr int CPL = HC / 64;
  constexpr int GROUP = C / CPL;
  const int n = (blockIdx.x * blockDim.x + threadIdx.x) >> 6;
  const int lane = threadIdx.x & 63;
  if (n >= NNODES) return;
  const int s0 = off[n], s1 = off[n + 1];

  float xrr[CPL], atr[CPL];
  if constexpr (CPL == 8) {
    unpack8(*(const int4*)(xr + (size_t)n * HC + lane * 8), xrr);
    const float4 a0 = *(const float4*)(att + lane * 8);
    const float4 a1 = *(const float4*)(att + lane * 8 + 4);
    atr[0] = a0.x; atr[1] = a0.y; atr[2] = a0.z; atr[3] = a0.w;
    atr[4] = a1.x; atr[5] = a1.y; atr[6] = a1.z; atr[7] = a1.w;
  } else {
    xrr[0] = b2f(xr[(size_t)n * HC + lane]);
    atr[0] = att[lane];
  }

  float m = -1e30f, s = 0.f;
  float acc[CPL] = {};

  int4 vnext = make_int4(0, 0, 0, 0);
  ushort_t unext = 0;
  int snext = 0;
  if (s0 < s1) {
    const int srcn = srcs[s0];
    if constexpr (CPL == 8) vnext = *(const int4*)(xl + (size_t)srcn * HC + lane * 8);
    else                    unext = xl[(size_t)srcn * HC + lane];
    if (s0 + 1 < s1) snext = srcs[s0 + 1];
  }
  for (int i = s0; i < s1; ++i) {
    int4 vcur = vnext; ushort_t ucur = unext;
    const int sn = snext;
    if (i + 2 < s1) snext = srcs[i + 2];
    if (i + 1 < s1) {
      if constexpr (CPL == 8) vnext = *(const int4*)(xl + (size_t)sn * HC + lane * 8);
      else                    unext = xl[(size_t)sn * HC + lane];
    }
    float zl[CPL];
    if constexpr (CPL == 8) unpack8(vcur, zl);
    else zl[0] = b2f(ucur);
    float e = 0.f;
    #pragma unroll
    for (int c = 0; c < CPL; ++c) {
      float z = zl[c] + xrr[c];
      z = (z > 0.f) ? z : 0.2f * z;
      e += z * atr[c];
    }
    #pragma unroll
    for (int o = 1; o < GROUP; o <<= 1)
      e += __shfl_xor(e, o, 64);
    if (e > m) {
      const float scale = __expf(m - e);
      s *= scale;
      #pragma unroll
      for (int c = 0; c < CPL; ++c) acc[c] *= scale;
      m = e;
    }
    const float w = __expf(e - m);
    s += w;
    #pragma unroll
    for (int c = 0; c < CPL; ++c) acc[c] += w * zl[c];
  }
  const float inv = 1.f / (s + 1e-16f);
  TO* po = out + (size_t)n * HC + lane * CPL;
  #pragma unroll
  for (int c = 0; c < CPL; ++c) {
    float v = acc[c] * inv + bias[lane * CPL + c];
    if (ELU) v = v > 0.f ? v : (__expf(v) - 1.f);
    stf(&po[c], v);
  }
}

// ---------- emergency: report ws_size via absmax ----------
__global__ void report_ws(float* __restrict__ out, float v) { out[0] = v; }

// ---------- orchestration ----------
extern "C" void kernel_launch(void* const* d_in, const int* in_sizes, int n_in,
                              void* d_out, int out_size, void* d_ws, size_t ws_size,
                              hipStream_t stream) {
  const float* x  = (const float*)d_in[0];
  const int*   ei = (const int*)d_in[1];
  float* out = (float*)d_out;
  char* ws = (char*)d_ws;

  ushort_t* hbuf = (ushort_t*)(ws);                   // N*512 bf16  51,200,000
  ushort_t* xlb  = (ushort_t*)(ws + 51200000ull);     // N*512 bf16
  ushort_t* xrb  = (ushort_t*)(ws + 102400000ull);    // N*512 bf16
  ushort_t* xb   = (ushort_t*)(ws + 153600000ull);    // N*128 bf16
  ushort_t* WtLR = (ushort_t*)(ws + 166400000ull);    // <=2MB
  int* bsum  = (int*)(ws + 168500000ull);
  int* bpref = (int*)(ws + 168501024ull);
  int* coff  = (int*)(ws + 168600000ull);             // N+1
  int* cpos  = (int*)(ws + 168800008ull);             // N
  int* cdeg  = (int*)(ws + 169000012ull);             // N
  int* srcs  = (int*)(ws + 169200016ull);             // E -> end 170,000,016

  if (ws_size < 170000016ull) {
    report_ws<<<1, 1, 0, stream>>>(out, (float)ws_size);
    return;
  }

  cast_x<<<(NNODES * 128 / 8 + 255) / 256, 256, 0, stream>>>(x, xb, NNODES * 128 / 8);
  csr_zero<<<(NNODES + 255) / 256, 256, 0, stream>>>(cdeg);
  csr_hist<<<(NEDGES + 255) / 256, 256, 0, stream>>>(ei, cdeg);
  scan_k1<<<SCAN_BLK, SCAN_TPB, 0, stream>>>(cdeg, bsum);
  scan_k2<<<1, 64, 0, stream>>>(bsum, bpref, coff);
  scan_k3<<<SCAN_BLK, SCAN_TPB, 0, stream>>>(cdeg, bpref, coff, cpos);
  csr_fill<<<(NEDGES + 255) / 256, 256, 0, stream>>>(ei, cpos, srcs);

  const int ngrid = (NNODES * 64 + 255) / 256;
  const int nrp = (NNODES + 127) / 128;               // 391 row panels

  for (int layer = 0; layer < 4; ++layer) {
    const int base = 2 + layer * 6;
    const float* Wl  = (const float*)d_in[base + 0];
    const float* bl  = (const float*)d_in[base + 1];
    const float* Wr  = (const float*)d_in[base + 2];
    const float* br  = (const float*)d_in[base + 3];
    const float* att = (const float*)d_in[base + 4];
    const float* b   = (const float*)d_in[base + 5];

    const ushort_t* A = (layer == 0) ? xb : hbuf;
    const int K  = (layer == 0) ? 128 : 512;
    const int Mo = (layer == 3) ? 64 : 512;
    const int ncb = 2 * Mo / 128;

    dim3 wg(2 * Mo / 32, K / 32);
    wt_prep_t<<<wg, 256, 0, stream>>>(Wl, Wr, WtLR, K, Mo);

    gemm2_pf2<<<ncb * nrp, 256, 0, stream>>>(A, WtLR, bl, br, xlb, xrb,
                                             NNODES, K, Mo, ncb);

    if (layer < 3) {
      csr_fused<4, 128, true, ushort_t><<<ngrid, 256, 0, stream>>>(
          coff, srcs, xlb, xrb, att, b, hbuf);
    } else {
      csr_fused<1, 64, false, float><<<ngrid, 256, 0, stream>>>(
          coff, srcs, xlb, xrb, att, b, out);
    }
  }
}